// Round 2
// baseline (826.025 us; speedup 1.0000x reference)
//
#include <hip/hip_runtime.h>

namespace {

constexpr int B = 8, C = 19, H = 512, W = 512;
constexpr int OH = 502, OW = 502;  // VALID conv output
constexpr int HW = H * W;

constexpr int TH = 32;             // output rows per tile
constexpr int TW = 54;             // output cols per tile
constexpr int IW = 64;             // input cols per tile (TW + 10)
constexpr int RPT = 8;             // output rows per thread, phase 1
constexpr int NJ = RPT + 10;       // input rows per thread, phase 1
constexpr int LW = 68;             // padded LDS row width (68%32=4 -> <=2-way banks)

// Gaussian g (win=11, sigma=1.5), normalized. Symmetric.
__device__ constexpr float G[11] = {
    0.00102838f, 0.00759876f, 0.03600077f, 0.10936070f, 0.21300553f,
    0.26601173f,
    0.21300553f, 0.10936070f, 0.03600077f, 0.00759876f, 0.00102838f};

// ---------------------------------------------------------------------------
// K1: softmax denominator (reciprocal), target compaction, accum zeroing.
// 4 pixels per thread via float4/int4. Grid = B*HW/1024 = 2048 blocks exactly.
// ---------------------------------------------------------------------------
__global__ __launch_bounds__(256) void denom_kernel(
    const float* __restrict__ pred, const int* __restrict__ target,
    float* __restrict__ rs, unsigned char* __restrict__ t8,
    float* __restrict__ accum) {
  int tid = blockIdx.x * 256 + threadIdx.x;
  if (blockIdx.x == 0 && threadIdx.x < B * C) accum[threadIdx.x] = 0.0f;
  int p4 = tid * 4;                 // first of 4 consecutive pixels
  int b = p4 / HW;
  int px = p4 - b * HW;             // HW % 4 == 0 -> same b for all 4
  const float4* pp = (const float4*)(pred + (size_t)b * C * HW + px);
  float4 s = {0.f, 0.f, 0.f, 0.f};
#pragma unroll
  for (int c = 0; c < C; ++c) {
    float4 v = pp[c * (HW / 4)];
    s.x += __expf(v.x);
    s.y += __expf(v.y);
    s.z += __expf(v.z);
    s.w += __expf(v.w);
  }
  float4 r;
  r.x = 1.0f / s.x;
  r.y = 1.0f / s.y;
  r.z = 1.0f / s.z;
  r.w = 1.0f / s.w;
  ((float4*)rs)[tid] = r;
  int4 t = ((const int4*)target)[tid];
  uchar4 tc;
  tc.x = (unsigned char)t.x;
  tc.y = (unsigned char)t.y;
  tc.z = (unsigned char)t.z;
  tc.w = (unsigned char)t.w;
  ((uchar4*)t8)[tid] = tc;
}

// ---------------------------------------------------------------------------
// K2: fused softmax + separable 11x11 conv of {p, p^2, p*t, t} + SSIM.
// Phase 1 (vertical, from global): 64 cols x 4 row-groups, 8 out rows/thread,
//   inputs held in registers (each loaded/squared/compared once).
// Phase 2 (horizontal, from LDS): 32 rows x 8 col-groups, 7 out cols/thread,
//   17 LDS reads/field, one fdividef per output.
// blockIdx.z = batch * 4 channel-groups ({5,5,5,4}) for grid smoothness.
// ---------------------------------------------------------------------------
__global__ __launch_bounds__(256, 4) void ssim_kernel(
    const float* __restrict__ pred, const float* __restrict__ rs,
    const unsigned char* __restrict__ t8, float* __restrict__ accum) {
  __shared__ float vOut[4][TH][LW];  // 34816 B

  const int tid = threadIdx.x;
  const int x0 = blockIdx.x * TW;
  const int y0 = blockIdx.y * TH;
  const int z = blockIdx.z;
  const int b = z >> 2;
  const int c0 = (z & 3) * 5;
  const int c1 = min(c0 + 5, C);
  const int ow = min(TW, OW - x0);
  const int oh = min(TH, OH - y0);

  // ---- phase-1 mapping: column per lane (coalesced), 4 row groups
  const int col = tid & 63;
  const int rg = tid >> 6;  // 0..3
  const int gc = min(x0 + col, W - 1);
  const int rbase = y0 + rg * RPT;

  // hoist 1/sumexp and target class for this thread's 18 input pixels
  float rsv[NJ];
  int tv[NJ];
#pragma unroll
  for (int j = 0; j < NJ; ++j) {
    int r = min(rbase + j, H - 1);
    int o = b * HW + r * W + gc;
    rsv[j] = rs[o];
    tv[j] = t8[o];
  }

  // ---- phase-2 mapping
  const int prow = tid >> 3;   // 0..31
  const int cg = tid & 7;      // 0..7
  const int cbase = cg * 7;    // 7 cols per thread (56 >= 54)

  for (int c = c0; c < c1; ++c) {
    __syncthreads();  // protect vOut against previous channel's readers

    // ---------------- phase 1: vertical 11-tap conv of 4 fields ----------
    const float* pc = pred + (size_t)(b * C + c) * HW;
    float aP[RPT] = {}, aP2[RPT] = {}, aPT[RPT] = {}, aT[RPT] = {};
#pragma unroll
    for (int j = 0; j < NJ; ++j) {
      int r = min(rbase + j, H - 1);
      float p = __expf(pc[r * W + gc]) * rsv[j];
      float p2 = p * p;
      bool hit = (tv[j] == c);
      float tf = hit ? 1.0f : 0.0f;
      float pt = hit ? p : 0.0f;
#pragma unroll
      for (int o = 0; o < RPT; ++o) {
        int g = j - o;
        if (g >= 0 && g < 11) {
          float gw = G[g];
          aP[o] = fmaf(gw, p, aP[o]);
          aP2[o] = fmaf(gw, p2, aP2[o]);
          aPT[o] = fmaf(gw, pt, aPT[o]);
          aT[o] = fmaf(gw, tf, aT[o]);
        }
      }
    }
#pragma unroll
    for (int o = 0; o < RPT; ++o) {
      int r = rg * RPT + o;
      vOut[0][r][col] = aP[o];
      vOut[1][r][col] = aP2[o];
      vOut[2][r][col] = aPT[o];
      vOut[3][r][col] = aT[o];
    }
    __syncthreads();

    // ---------------- phase 2: horizontal 11-tap conv + SSIM -------------
    float mres[4][7];
#pragma unroll
    for (int f = 0; f < 4; ++f) {
      float vin[17];
#pragma unroll
      for (int k = 0; k < 17; ++k) vin[k] = vOut[f][prow][cbase + k];
#pragma unroll
      for (int o = 0; o < 7; ++o) {
        float s = 0.0f;
#pragma unroll
        for (int j = 0; j < 11; ++j) s = fmaf(G[j], vin[o + j], s);
        mres[f][o] = s;
      }
    }

    float acc = 0.0f;
    if (prow < oh) {
#pragma unroll
      for (int o = 0; o < 7; ++o) {
        if (cbase + o < ow) {
          float mu1 = mres[0][o];
          float dp2 = mres[1][o];
          float dpt = mres[2][o];
          float mu2 = mres[3][o];
          float mu1sq = mu1 * mu1;
          float mu2sq = mu2 * mu2;
          float mu12 = mu1 * mu2;
          float var1 = dp2 - mu1sq;
          float var2 = mu2 - mu2sq;  // t one-hot: dwconv(t^2) == mu2
          float covar = dpt - mu12;
          const float c1c = 1e-4f, c2c = 9e-4f;
          float num = (2.0f * mu12 + c1c) * (2.0f * covar + c2c);
          float den = (mu1sq + mu2sq + c1c) * (var1 + var2 + c2c);
          acc += __fdividef(num, den);
        }
      }
    }

    // wave reduce + one atomic per wave per channel (no extra barrier)
    for (int o2 = 32; o2 > 0; o2 >>= 1) acc += __shfl_down(acc, o2);
    if ((tid & 63) == 0) atomicAdd(&accum[b * C + c], acc);
  }
}

// ---------------------------------------------------------------------------
// K3: final reduction: per-(b,c) mean, relu, 1 - mean
// ---------------------------------------------------------------------------
__global__ __launch_bounds__(256) void finish_kernel(
    const float* __restrict__ accum, float* __restrict__ out) {
  __shared__ float red[4];
  int tid = threadIdx.x;
  float v = 0.0f;
  if (tid < B * C) {
    float m = accum[tid] * (1.0f / (float)(OH * OW));
    v = m > 0.0f ? m : 0.0f;
  }
  for (int off = 32; off > 0; off >>= 1) v += __shfl_down(v, off);
  if ((tid & 63) == 0) red[tid >> 6] = v;
  __syncthreads();
  if (tid == 0)
    out[0] = 1.0f - (red[0] + red[1] + red[2] + red[3]) / (float)(B * C);
}

}  // namespace

extern "C" void kernel_launch(void* const* d_in, const int* in_sizes, int n_in,
                              void* d_out, int out_size, void* d_ws,
                              size_t ws_size, hipStream_t stream) {
  const float* pred = (const float*)d_in[0];
  const int* target = (const int*)d_in[1];
  float* out = (float*)d_out;

  // workspace: rs (B*HW f32) | t8 (B*HW u8) | accum (B*C f32)
  float* rs = (float*)d_ws;
  unsigned char* t8 = (unsigned char*)d_ws + (size_t)B * HW * sizeof(float);
  float* accum = (float*)((char*)d_ws + (size_t)B * HW * 5);

  denom_kernel<<<B * HW / 1024, 256, 0, stream>>>(pred, target, rs, t8, accum);
  dim3 grid((OW + TW - 1) / TW, (OH + TH - 1) / TH, B * 4);
  ssim_kernel<<<grid, 256, 0, stream>>>(pred, rs, t8, accum);
  finish_kernel<<<1, 256, 0, stream>>>(accum, out);
}

// Round 3
// 792.652 us; speedup vs baseline: 1.0421x; 1.0421x over previous
//
#include <hip/hip_runtime.h>

namespace {

constexpr int B = 8, C = 19, H = 512, W = 512;
constexpr int OH = 502, OW = 502;  // VALID conv output
constexpr int HW = H * W;

constexpr int TH = 32;        // output rows per tile
constexpr int TW = 54;        // output cols per tile (input cols = 64)
constexpr int RPT = 8;        // output rows per thread, phase 1
constexpr int NJ = RPT + 10;  // input rows per thread, phase 1
constexpr int LW = 68;        // padded LDS row width: (4*prow+7*cg) mod 32
                              // -> exactly 2 lanes/bank (free); odd stride 7
                              // keeps phase-2 reads scalar b32 (no misaligned
                              // b128 -> no 8/16-way conflicts)

// Gaussian g (win=11, sigma=1.5), normalized. Symmetric.
__device__ constexpr float G[11] = {
    0.00102838f, 0.00759876f, 0.03600077f, 0.10936070f, 0.21300553f,
    0.26601173f,
    0.21300553f, 0.10936070f, 0.03600077f, 0.00759876f, 0.00102838f};

// ---------------------------------------------------------------------------
// K1: softmax denominator (reciprocal), target compaction, accum zeroing.
// ---------------------------------------------------------------------------
__global__ __launch_bounds__(256) void denom_kernel(
    const float* __restrict__ pred, const int* __restrict__ target,
    float* __restrict__ rs, unsigned char* __restrict__ t8,
    float* __restrict__ accum) {
  int tid = blockIdx.x * 256 + threadIdx.x;
  if (blockIdx.x == 0 && threadIdx.x < B * C) accum[threadIdx.x] = 0.0f;
  int p4 = tid * 4;
  int b = p4 / HW;
  int px = p4 - b * HW;  // HW % 4 == 0 -> same b for all 4 pixels
  const float4* pp = (const float4*)(pred + (size_t)b * C * HW + px);
  float4 s = {0.f, 0.f, 0.f, 0.f};
#pragma unroll
  for (int c = 0; c < C; ++c) {
    float4 v = pp[c * (HW / 4)];
    s.x += __expf(v.x);
    s.y += __expf(v.y);
    s.z += __expf(v.z);
    s.w += __expf(v.w);
  }
  float4 r;
  r.x = 1.0f / s.x;
  r.y = 1.0f / s.y;
  r.z = 1.0f / s.z;
  r.w = 1.0f / s.w;
  ((float4*)rs)[tid] = r;
  int4 t = ((const int4*)target)[tid];
  uchar4 tc;
  tc.x = (unsigned char)t.x;
  tc.y = (unsigned char)t.y;
  tc.z = (unsigned char)t.z;
  tc.w = (unsigned char)t.w;
  ((uchar4*)t8)[tid] = tc;
}

// ---------------------------------------------------------------------------
// K2: fused softmax + separable 11x11 conv of {p, p^2, p*t, t} + SSIM.
// Phase 1: vertical conv from global, col-per-lane (coalesced), 8 rows/thread
//          in registers; rs/t8 read per-j per-channel (tile is L1/L2-hot --
//          NO register hoist across the channel loop; that spilled in R2).
// Phase 2: horizontal conv from LDS, 7 cols/thread, one fdividef per output.
// ---------------------------------------------------------------------------
__global__ __launch_bounds__(256, 4) void ssim_kernel(
    const float* __restrict__ pred, const float* __restrict__ rs,
    const unsigned char* __restrict__ t8, float* __restrict__ accum) {
  __shared__ float vOut[4][TH][LW];  // 34816 B -> 4 blocks/CU

  const int tid = threadIdx.x;
  const int x0 = blockIdx.x * TW;
  const int y0 = blockIdx.y * TH;
  const int z = blockIdx.z;
  const int b = z >> 2;
  const int c0 = (z & 3) * 5;
  const int c1 = min(c0 + 5, C);
  const int ow = min(TW, OW - x0);
  const int oh = min(TH, OH - y0);

  // phase-1 mapping: column per lane, 4 row-groups
  const int col = tid & 63;
  const int rg = tid >> 6;
  const int gc = min(x0 + col, W - 1);
  const int rbase = y0 + rg * RPT;

  // phase-2 mapping
  const int prow = tid >> 3;  // 0..31
  const int cg = tid & 7;     // 0..7
  const int cbase = cg * 7;   // 56 >= 54 cols covered

  const float* rsb = rs + b * HW;
  const unsigned char* tb = t8 + b * HW;

  for (int c = c0; c < c1; ++c) {
    __syncthreads();  // protect vOut against previous channel's readers

    // ---------------- phase 1: vertical 11-tap conv of 4 fields ----------
    const float* pc = pred + (size_t)(b * C + c) * HW;
    float aP[RPT] = {}, aP2[RPT] = {}, aPT[RPT] = {}, aT[RPT] = {};
#pragma unroll
    for (int j = 0; j < NJ; ++j) {
      int r = min(rbase + j, H - 1);
      int o = r * W + gc;
      float p = __expf(pc[o]) * rsb[o];  // softmax prob, computed once
      float p2 = p * p;
      bool hit = ((int)tb[o] == c);
      float tf = hit ? 1.0f : 0.0f;
      float pt = hit ? p : 0.0f;
#pragma unroll
      for (int oo = 0; oo < RPT; ++oo) {
        int g = j - oo;
        if (g >= 0 && g < 11) {
          float gw = G[g];
          aP[oo] = fmaf(gw, p, aP[oo]);
          aP2[oo] = fmaf(gw, p2, aP2[oo]);
          aPT[oo] = fmaf(gw, pt, aPT[oo]);
          aT[oo] = fmaf(gw, tf, aT[oo]);
        }
      }
    }
#pragma unroll
    for (int oo = 0; oo < RPT; ++oo) {
      int r = rg * RPT + oo;
      vOut[0][r][col] = aP[oo];
      vOut[1][r][col] = aP2[oo];
      vOut[2][r][col] = aPT[oo];
      vOut[3][r][col] = aT[oo];
    }
    __syncthreads();

    // ---------------- phase 2: horizontal 11-tap conv + SSIM -------------
    float mres[4][7];
#pragma unroll
    for (int f = 0; f < 4; ++f) {
      float vin[17];
#pragma unroll
      for (int k = 0; k < 17; ++k) vin[k] = vOut[f][prow][cbase + k];
#pragma unroll
      for (int oo = 0; oo < 7; ++oo) {
        float s = 0.0f;
#pragma unroll
        for (int j = 0; j < 11; ++j) s = fmaf(G[j], vin[oo + j], s);
        mres[f][oo] = s;
      }
    }

    float acc = 0.0f;
    if (prow < oh) {
#pragma unroll
      for (int oo = 0; oo < 7; ++oo) {
        if (cbase + oo < ow) {
          float mu1 = mres[0][oo];
          float dp2 = mres[1][oo];
          float dpt = mres[2][oo];
          float mu2 = mres[3][oo];
          float mu1sq = mu1 * mu1;
          float mu2sq = mu2 * mu2;
          float mu12 = mu1 * mu2;
          float var1 = dp2 - mu1sq;
          float var2 = mu2 - mu2sq;  // t one-hot: dwconv(t^2) == mu2
          float covar = dpt - mu12;
          const float c1c = 1e-4f, c2c = 9e-4f;
          float num = (2.0f * mu12 + c1c) * (2.0f * covar + c2c);
          float den = (mu1sq + mu2sq + c1c) * (var1 + var2 + c2c);
          acc += __fdividef(num, den);
        }
      }
    }

    // wave reduce + one atomic per wave per channel
    for (int o2 = 32; o2 > 0; o2 >>= 1) acc += __shfl_down(acc, o2);
    if ((tid & 63) == 0) atomicAdd(&accum[b * C + c], acc);
  }
}

// ---------------------------------------------------------------------------
// K3: final reduction: per-(b,c) mean, relu, 1 - mean
// ---------------------------------------------------------------------------
__global__ __launch_bounds__(256) void finish_kernel(
    const float* __restrict__ accum, float* __restrict__ out) {
  __shared__ float red[4];
  int tid = threadIdx.x;
  float v = 0.0f;
  if (tid < B * C) {
    float m = accum[tid] * (1.0f / (float)(OH * OW));
    v = m > 0.0f ? m : 0.0f;
  }
  for (int off = 32; off > 0; off >>= 1) v += __shfl_down(v, off);
  if ((tid & 63) == 0) red[tid >> 6] = v;
  __syncthreads();
  if (tid == 0)
    out[0] = 1.0f - (red[0] + red[1] + red[2] + red[3]) / (float)(B * C);
}

}  // namespace

extern "C" void kernel_launch(void* const* d_in, const int* in_sizes, int n_in,
                              void* d_out, int out_size, void* d_ws,
                              size_t ws_size, hipStream_t stream) {
  const float* pred = (const float*)d_in[0];
  const int* target = (const int*)d_in[1];
  float* out = (float*)d_out;

  // workspace: rs (B*HW f32) | t8 (B*HW u8) | accum (B*C f32)
  float* rs = (float*)d_ws;
  unsigned char* t8 = (unsigned char*)d_ws + (size_t)B * HW * sizeof(float);
  float* accum = (float*)((char*)d_ws + (size_t)B * HW * 5);

  denom_kernel<<<B * HW / 1024, 256, 0, stream>>>(pred, target, rs, t8, accum);
  dim3 grid((OW + TW - 1) / TW, (OH + TH - 1) / TH, B * 4);
  ssim_kernel<<<grid, 256, 0, stream>>>(pred, rs, t8, accum);
  finish_kernel<<<1, 256, 0, stream>>>(accum, out);
}

// Round 7
// 774.641 us; speedup vs baseline: 1.0663x; 1.0233x over previous
//
#include <hip/hip_runtime.h>
#include <hip/hip_fp16.h>

namespace {

constexpr int B = 8, C = 19, H = 512, W = 512, HW = H * W;
constexpr int OH = 502, OW = 502;  // VALID conv output
constexpr int TH = 32, TW = 54;    // output tile
constexpr int IH = 42, IW = 64;    // input tile (TH+10 rows, 64 cols)
constexpr int LW = 76;             // vOut padded width (u32 units)

// Gaussian g (win=11, sigma=1.5), normalized. Symmetric.
__device__ constexpr float G[11] = {
    0.00102838f, 0.00759876f, 0.03600077f, 0.10936070f, 0.21300553f,
    0.26601173f,
    0.21300553f, 0.10936070f, 0.03600077f, 0.00759876f, 0.00102838f};

// ===========================================================================
// PRIMARY PATH (needs ~76 MiB workspace for f16 softmax probabilities)
// ===========================================================================

// K1: full softmax -> f16 probabilities + accum zeroing. 4 px/thread.
__global__ __launch_bounds__(256, 4) void softmax_kernel(
    const float* __restrict__ pred, __half* __restrict__ pH,
    float* __restrict__ accum) {
  const int tid = blockIdx.x * 256 + threadIdx.x;
  if (blockIdx.x == 0 && threadIdx.x < B * C) accum[threadIdx.x] = 0.0f;
  const int p4 = tid * 4;
  const int b = p4 / HW;
  const int px = p4 - b * HW;  // HW%4==0 -> same b for all 4
  const float* base = pred + (size_t)b * C * HW + px;
  uint2 eh[C];
  float sx = 0.f, sy = 0.f, sz = 0.f, sw = 0.f;
#pragma unroll
  for (int c = 0; c < C; ++c) {
    float4 v = *(const float4*)(base + (size_t)c * HW);
    float ex = __expf(v.x), ey = __expf(v.y);
    float ez = __expf(v.z), ew = __expf(v.w);
    sx += ex; sy += ey; sz += ez; sw += ew;
    __half2 l = __floats2half2_rn(ex, ey);
    __half2 h = __floats2half2_rn(ez, ew);
    eh[c].x = *(const unsigned*)&l;
    eh[c].y = *(const unsigned*)&h;
  }
  const float rx = 1.f / sx, ry = 1.f / sy, rz = 1.f / sz, rw = 1.f / sw;
  __half* outb = pH + (size_t)b * C * HW + px;
#pragma unroll
  for (int c = 0; c < C; ++c) {
    __half2 l = *(const __half2*)&eh[c].x;
    __half2 h = *(const __half2*)&eh[c].y;
    __half2 pl = __floats2half2_rn(__low2float(l) * rx, __high2float(l) * ry);
    __half2 ph = __floats2half2_rn(__low2float(h) * rz, __high2float(h) * rw);
    uint2 o;
    o.x = *(const unsigned*)&pl;
    o.y = *(const unsigned*)&ph;
    *(uint2*)(outb + (size_t)c * HW) = o;
  }
}

// K2: separable 11x11 conv of {p, p^2, p*t, t} from f16 p + SSIM reduce.
// All hot-loop inputs come from LDS (pTu f16 tile, tmask one-hot bits).
// Next channel's tile: loads issued at phase-2 start, ds_write at its end
// (T14 split). vOut packed f16x2.
__global__ __launch_bounds__(256, 4) void ssim_kernel(
    const __half* __restrict__ pH, const int* __restrict__ target,
    float* __restrict__ accum) {
  __shared__ unsigned pTu[IH * IW / 2];  // 5376 B
  __shared__ unsigned tmask[IH * IW];    // 10752 B
  __shared__ unsigned vOutU[2][TH][LW];  // 19456 B -> total 35584 B, 4 blk/CU
  const int tid = threadIdx.x;
  const int x0 = blockIdx.x * TW;
  const int y0 = blockIdx.y * TH;
  const int z = blockIdx.z;
  const int b = z >> 2;
  const int c0 = (z & 3) * 5;
  const int c1 = min(c0 + 5, C);
  const int ow = min(TW, OW - x0);
  const int oh = min(TH, OH - y0);

  const int col = tid & 63;   // phase 1: column per lane
  const int rg = tid >> 6;    // wave id = row-group
  const int rb = rg * 8;
  const int prow = tid >> 3;  // phase 2: row per 8-thread group
  const int cg = tid & 7;
  const int cbase = cg * 8;

  {  // one-hot mask tile (once per block)
    const int* tb = target + b * HW;
    for (int w = tid; w < IH * IW; w += 256) {
      int r = w >> 6, cc = w & 63;
      int t = tb[min(y0 + r, H - 1) * W + min(x0 + cc, W - 1)];
      tmask[w] = 1u << t;
    }
  }
  {  // stage first channel's p tile (1344 u32 words)
    const __half* pb = pH + (size_t)(b * C + c0) * HW;
#pragma unroll
    for (int k = 0; k < 6; ++k) {
      int w = tid + k * 256;
      if (w < IH * IW / 2) {
        int r = w >> 5, cw = w & 31;
        pTu[w] = *(const unsigned*)(pb + min(y0 + r, H - 1) * W +
                                    min(x0 + 2 * cw, W - 2));
      }
    }
  }

  float* accp = accum + b * C;
  for (int c = c0; c < c1; ++c) {
    __syncthreads();  // pTu stores visible; vOut free of prev readers

    // ---- phase 1: vertical 11-tap conv of 4 fields
    if (rb < oh) {
      float aP[8] = {}, aP2[8] = {}, aPT[8] = {}, aT[8] = {};
#pragma unroll
      for (int j = 0; j < 18; ++j) {
        int lr = rb + j;
        float pv = __half2float(((const __half*)pTu)[lr * IW + col]);
        unsigned m = tmask[lr * IW + col];
        float tf = (float)((m >> c) & 1u);
        float p2 = pv * pv;
        float pt = tf * pv;
#pragma unroll
        for (int oo = 0; oo < 8; ++oo) {
          int g = j - oo;
          if (g >= 0 && g < 11) {
            float gw = G[g];
            aP[oo] = fmaf(gw, pv, aP[oo]);
            aP2[oo] = fmaf(gw, p2, aP2[oo]);
            aPT[oo] = fmaf(gw, pt, aPT[oo]);
            aT[oo] = fmaf(gw, tf, aT[oo]);
          }
        }
      }
#pragma unroll
      for (int oo = 0; oo < 8; ++oo) {
        int r = rb + oo;
        __half2 a = __floats2half2_rn(aP[oo], aP2[oo]);
        __half2 bb = __floats2half2_rn(aPT[oo], aT[oo]);
        vOutU[0][r][col] = *(const unsigned*)&a;
        vOutU[1][r][col] = *(const unsigned*)&bb;
      }
    }
    __syncthreads();

    // ---- phase 2: stage(c+1) issue early + horizontal conv + SSIM
    const bool more = (c + 1) < c1;
    unsigned R2[6];
    if (more) {
      const __half* pn = pH + (size_t)(b * C + c + 1) * HW;
#pragma unroll
      for (int k = 0; k < 6; ++k) {
        int w = tid + k * 256;
        unsigned v = 0;
        if (w < IH * IW / 2) {
          int r = w >> 5, cw = w & 31;
          v = *(const unsigned*)(pn + min(y0 + r, H - 1) * W +
                                 min(x0 + 2 * cw, W - 2));
        }
        R2[k] = v;
      }
    }

    float acc = 0.0f;
    if (rb < oh) {
      float mu1[8] = {}, dp2[8] = {}, dpt[8] = {}, mu2[8] = {};
#pragma unroll
      for (int gsel = 0; gsel < 2; ++gsel) {
        unsigned vin[18];
#pragma unroll
        for (int k = 0; k < 18; ++k) vin[k] = vOutU[gsel][prow][cbase + k];
#pragma unroll
        for (int j = 0; j < 18; ++j) {
          __half2 hv = *(const __half2*)&vin[j];
          float lo = __low2float(hv), hi = __high2float(hv);
#pragma unroll
          for (int oo = 0; oo < 8; ++oo) {
            int g = j - oo;
            if (g >= 0 && g < 11) {
              float gw = G[g];
              if (gsel == 0) {
                mu1[oo] = fmaf(gw, lo, mu1[oo]);
                dp2[oo] = fmaf(gw, hi, dp2[oo]);
              } else {
                dpt[oo] = fmaf(gw, lo, dpt[oo]);
                mu2[oo] = fmaf(gw, hi, mu2[oo]);
              }
            }
          }
        }
      }
      if (prow < oh) {
#pragma unroll
        for (int oo = 0; oo < 8; ++oo) {
          if (cbase + oo < ow) {
            float m1 = mu1[oo], m2 = mu2[oo];
            float m1s = m1 * m1, m2s = m2 * m2, m12 = m1 * m2;
            float v1 = dp2[oo] - m1s;
            float v2 = m2 - m2s;  // t one-hot: dwconv(t^2) == mu2
            float cv = dpt[oo] - m12;
            float num = (2.f * m12 + 1e-4f) * (2.f * cv + 9e-4f);
            float den = (m1s + m2s + 1e-4f) * (v1 + v2 + 9e-4f);
            acc += __fdividef(num, den);
          }
        }
      }
      for (int o2 = 32; o2 > 0; o2 >>= 1) acc += __shfl_down(acc, o2);
      if ((tid & 63) == 0) atomicAdd(accp + c, acc);
    }

    if (more) {  // write-late: phase-1 readers of pTu done at mid barrier
#pragma unroll
      for (int k = 0; k < 6; ++k) {
        int w = tid + k * 256;
        if (w < IH * IW / 2) pTu[w] = R2[k];
      }
    }
  }
}

// ===========================================================================
// FALLBACK PATH (R3 design, ~10.5 MiB workspace) — used only if ws too small
// ===========================================================================

__global__ __launch_bounds__(256) void denom_kernel(
    const float* __restrict__ pred, const int* __restrict__ target,
    float* __restrict__ rs, unsigned char* __restrict__ t8,
    float* __restrict__ accum) {
  int tid = blockIdx.x * 256 + threadIdx.x;
  if (blockIdx.x == 0 && threadIdx.x < B * C) accum[threadIdx.x] = 0.0f;
  int p4 = tid * 4;
  int b = p4 / HW;
  int px = p4 - b * HW;
  const float4* pp = (const float4*)(pred + (size_t)b * C * HW + px);
  float4 s = {0.f, 0.f, 0.f, 0.f};
#pragma unroll
  for (int c = 0; c < C; ++c) {
    float4 v = pp[c * (HW / 4)];
    s.x += __expf(v.x);
    s.y += __expf(v.y);
    s.z += __expf(v.z);
    s.w += __expf(v.w);
  }
  float4 r;
  r.x = 1.0f / s.x; r.y = 1.0f / s.y; r.z = 1.0f / s.z; r.w = 1.0f / s.w;
  ((float4*)rs)[tid] = r;
  int4 t = ((const int4*)target)[tid];
  uchar4 tc;
  tc.x = (unsigned char)t.x; tc.y = (unsigned char)t.y;
  tc.z = (unsigned char)t.z; tc.w = (unsigned char)t.w;
  ((uchar4*)t8)[tid] = tc;
}

__global__ __launch_bounds__(256, 4) void ssim_f32_kernel(
    const float* __restrict__ pred, const float* __restrict__ rs,
    const unsigned char* __restrict__ t8, float* __restrict__ accum) {
  __shared__ float vOut[4][TH][68];
  const int tid = threadIdx.x;
  const int x0 = blockIdx.x * TW;
  const int y0 = blockIdx.y * TH;
  const int z = blockIdx.z;
  const int b = z >> 2;
  const int c0 = (z & 3) * 5;
  const int c1 = min(c0 + 5, C);
  const int ow = min(TW, OW - x0);
  const int oh = min(TH, OH - y0);
  const int col = tid & 63;
  const int rg = tid >> 6;
  const int gc = min(x0 + col, W - 1);
  const int rbase = y0 + rg * 8;
  const int prow = tid >> 3;
  const int cg = tid & 7;
  const int cbase = cg * 7;
  const float* rsb = rs + b * HW;
  const unsigned char* tb = t8 + b * HW;

  for (int c = c0; c < c1; ++c) {
    __syncthreads();
    const float* pc = pred + (size_t)(b * C + c) * HW;
    float aP[8] = {}, aP2[8] = {}, aPT[8] = {}, aT[8] = {};
#pragma unroll
    for (int j = 0; j < 18; ++j) {
      int r = min(rbase + j, H - 1);
      int o = r * W + gc;
      float p = __expf(pc[o]) * rsb[o];
      float p2 = p * p;
      bool hit = ((int)tb[o] == c);
      float tf = hit ? 1.0f : 0.0f;
      float pt = hit ? p : 0.0f;
#pragma unroll
      for (int oo = 0; oo < 8; ++oo) {
        int g = j - oo;
        if (g >= 0 && g < 11) {
          float gw = G[g];
          aP[oo] = fmaf(gw, p, aP[oo]);
          aP2[oo] = fmaf(gw, p2, aP2[oo]);
          aPT[oo] = fmaf(gw, pt, aPT[oo]);
          aT[oo] = fmaf(gw, tf, aT[oo]);
        }
      }
    }
#pragma unroll
    for (int oo = 0; oo < 8; ++oo) {
      int r = rg * 8 + oo;
      vOut[0][r][col] = aP[oo];
      vOut[1][r][col] = aP2[oo];
      vOut[2][r][col] = aPT[oo];
      vOut[3][r][col] = aT[oo];
    }
    __syncthreads();

    float mres[4][7];
#pragma unroll
    for (int f = 0; f < 4; ++f) {
      float vin[17];
#pragma unroll
      for (int k = 0; k < 17; ++k) vin[k] = vOut[f][prow][cbase + k];
#pragma unroll
      for (int oo = 0; oo < 7; ++oo) {
        float s = 0.0f;
#pragma unroll
        for (int j = 0; j < 11; ++j) s = fmaf(G[j], vin[oo + j], s);
        mres[f][oo] = s;
      }
    }
    float acc = 0.0f;
    if (prow < oh) {
#pragma unroll
      for (int oo = 0; oo < 7; ++oo) {
        if (cbase + oo < ow) {
          float m1 = mres[0][oo], m2 = mres[3][oo];
          float m1s = m1 * m1, m2s = m2 * m2, m12 = m1 * m2;
          float v1 = mres[1][oo] - m1s;
          float v2 = m2 - m2s;
          float cv = mres[2][oo] - m12;
          float num = (2.f * m12 + 1e-4f) * (2.f * cv + 9e-4f);
          float den = (m1s + m2s + 1e-4f) * (v1 + v2 + 9e-4f);
          acc += __fdividef(num, den);
        }
      }
    }
    for (int o2 = 32; o2 > 0; o2 >>= 1) acc += __shfl_down(acc, o2);
    if ((tid & 63) == 0) atomicAdd(&accum[b * C + c], acc);
  }
}

// K3: final reduction: per-(b,c) mean, relu, 1 - mean
__global__ __launch_bounds__(256) void finish_kernel(
    const float* __restrict__ accum, float* __restrict__ out) {
  __shared__ float red[4];
  int tid = threadIdx.x;
  float v = 0.0f;
  if (tid < B * C) {
    float m = accum[tid] * (1.0f / (float)(OH * OW));
    v = m > 0.0f ? m : 0.0f;
  }
  for (int off = 32; off > 0; off >>= 1) v += __shfl_down(v, off);
  if ((tid & 63) == 0) red[tid >> 6] = v;
  __syncthreads();
  if (tid == 0)
    out[0] = 1.0f - (red[0] + red[1] + red[2] + red[3]) / (float)(B * C);
}

}  // namespace

extern "C" void kernel_launch(void* const* d_in, const int* in_sizes, int n_in,
                              void* d_out, int out_size, void* d_ws,
                              size_t ws_size, hipStream_t stream) {
  const float* pred = (const float*)d_in[0];
  const int* target = (const int*)d_in[1];
  float* out = (float*)d_out;

  const size_t needH = (size_t)B * C * HW * 2 + (size_t)B * C * 4;
  dim3 grid((OW + TW - 1) / TW, (OH + TH - 1) / TH, B * 4);

  if (ws_size >= needH) {
    // primary: pH (76 MiB f16) | accum
    __half* pH = (__half*)d_ws;
    float* accum = (float*)((char*)d_ws + (size_t)B * C * HW * 2);
    softmax_kernel<<<B * HW / 1024, 256, 0, stream>>>(pred, pH, accum);
    ssim_kernel<<<grid, 256, 0, stream>>>(pH, target, accum);
    finish_kernel<<<1, 256, 0, stream>>>(accum, out);
  } else {
    // fallback: rs (8 MiB f32) | t8 (2 MiB u8) | accum
    float* rs = (float*)d_ws;
    unsigned char* t8 = (unsigned char*)d_ws + (size_t)B * HW * 4;
    float* accum = (float*)((char*)d_ws + (size_t)B * HW * 5);
    denom_kernel<<<B * HW / 1024, 256, 0, stream>>>(pred, target, rs, t8,
                                                    accum);
    ssim_f32_kernel<<<grid, 256, 0, stream>>>(pred, rs, t8, accum);
    finish_kernel<<<1, 256, 0, stream>>>(accum, out);
  }
}

// Round 9
// 692.745 us; speedup vs baseline: 1.1924x; 1.1182x over previous
//
#include <hip/hip_runtime.h>
#include <hip/hip_fp16.h>

namespace {

constexpr int B = 8, C = 19, H = 512, W = 512, HW = H * W;
constexpr int OH = 502, OW = 502;  // VALID conv output
constexpr int TH = 32, TW = 54;    // output tile
constexpr int IH = 42, IW = 64;    // input tile (TH+10 rows, 64 cols)
constexpr int LW = 77;             // vOut padded width (u32 units), ODD:
                                   // phase-2 bank = (13*prow+8*cg+k)%32 ->
                                   // exactly 2 lanes/bank (free, m136)

// Gaussian g (win=11, sigma=1.5), normalized. Symmetric.
__device__ constexpr float G[11] = {
    0.00102838f, 0.00759876f, 0.03600077f, 0.10936070f, 0.21300553f,
    0.26601173f,
    0.21300553f, 0.10936070f, 0.03600077f, 0.00759876f, 0.00102838f};

// ===========================================================================
// PRIMARY PATH (needs ~76 MiB workspace for f16 softmax probabilities)
// ===========================================================================

// K1: full softmax -> f16 probabilities + accum zeroing. 2 px/thread keeps
// the live set ~32 VGPRs (eh[19] packed half2) -> no spill at any tier.
__global__ __launch_bounds__(256) void softmax_kernel(
    const float* __restrict__ pred, __half* __restrict__ pH,
    float* __restrict__ accum) {
  const int tid = blockIdx.x * 256 + threadIdx.x;
  if (blockIdx.x == 0 && threadIdx.x < B * C) accum[threadIdx.x] = 0.0f;
  const int p2 = tid * 2;
  const int b = p2 / HW;
  const int px = p2 - b * HW;  // HW%2==0 -> same b for both
  const float* base = pred + (size_t)b * C * HW + px;
  unsigned eh[C];
  float sx = 0.f, sy = 0.f;
#pragma unroll
  for (int c = 0; c < C; ++c) {
    float2 v = *(const float2*)(base + (size_t)c * HW);
    float ex = __expf(v.x), ey = __expf(v.y);
    sx += ex;
    sy += ey;
    __half2 h = __floats2half2_rn(ex, ey);
    eh[c] = *(const unsigned*)&h;
  }
  const float rx = 1.f / sx, ry = 1.f / sy;
  __half* outb = pH + (size_t)b * C * HW + px;
#pragma unroll
  for (int c = 0; c < C; ++c) {
    __half2 h = *(const __half2*)&eh[c];
    __half2 p = __floats2half2_rn(__low2float(h) * rx, __high2float(h) * ry);
    *(unsigned*)(outb + (size_t)c * HW) = *(const unsigned*)&p;
  }
}

// K2: separable 11x11 conv of {p, p^2, p*t, t} from f16 p + SSIM reduce.
// All hot-loop inputs come from LDS. waves_per_eu(4,4) pins the allocator to
// the 128-VGPR tier (R2/R3/R7 spilled ~30 regs chasing the 64-VGPR/8-wave
// tier -> 33-245 MB scratch traffic). LDS caps us at 4 blocks/CU anyway.
__global__ __launch_bounds__(256)
__attribute__((amdgpu_waves_per_eu(4, 4))) void ssim_kernel(
    const __half* __restrict__ pH, const int* __restrict__ target,
    float* __restrict__ accum) {
  __shared__ unsigned pTu[IH * IW / 2];  // 5376 B
  __shared__ unsigned tmask[IH * IW];    // 10752 B
  __shared__ unsigned vOutU[2][TH][LW];  // 19712 B -> total 35840 B, 4 blk/CU
  const int tid = threadIdx.x;
  const int x0 = blockIdx.x * TW;
  const int y0 = blockIdx.y * TH;
  const int z = blockIdx.z;
  const int b = z >> 2;
  const int c0 = (z & 3) * 5;
  const int c1 = min(c0 + 5, C);
  const int ow = min(TW, OW - x0);
  const int oh = min(TH, OH - y0);

  const int col = tid & 63;   // phase 1: column per lane
  const int rg = tid >> 6;    // wave id = row-group
  const int rb = rg * 8;
  const int prow = tid >> 3;  // phase 2: row per 8-thread group
  const int cg = tid & 7;
  const int cbase = cg * 8;

  {  // one-hot mask tile (once per block)
    const int* tb = target + b * HW;
    for (int w = tid; w < IH * IW; w += 256) {
      int r = w >> 6, cc = w & 63;
      int t = tb[min(y0 + r, H - 1) * W + min(x0 + cc, W - 1)];
      tmask[w] = 1u << t;
    }
  }
  {  // stage first channel's p tile (1344 u32 words)
    const __half* pb = pH + (size_t)(b * C + c0) * HW;
#pragma unroll
    for (int k = 0; k < 6; ++k) {
      int w = tid + k * 256;
      if (w < IH * IW / 2) {
        int r = w >> 5, cw = w & 31;
        pTu[w] = *(const unsigned*)(pb + min(y0 + r, H - 1) * W +
                                    min(x0 + 2 * cw, W - 2));
      }
    }
  }

  float* accp = accum + b * C;
  for (int c = c0; c < c1; ++c) {
    __syncthreads();  // pTu stores visible; vOut free of prev readers

    // ---- phase 1: vertical 11-tap conv of 4 fields
    if (rb < oh) {
      float aP[8] = {}, aP2[8] = {}, aPT[8] = {}, aT[8] = {};
#pragma unroll
      for (int j = 0; j < 18; ++j) {
        int lr = rb + j;
        float pv = __half2float(((const __half*)pTu)[lr * IW + col]);
        unsigned m = tmask[lr * IW + col];
        float tf = (float)((m >> c) & 1u);
        float p2 = pv * pv;
        float pt = tf * pv;
#pragma unroll
        for (int oo = 0; oo < 8; ++oo) {
          int g = j - oo;
          if (g >= 0 && g < 11) {
            float gw = G[g];
            aP[oo] = fmaf(gw, pv, aP[oo]);
            aP2[oo] = fmaf(gw, p2, aP2[oo]);
            aPT[oo] = fmaf(gw, pt, aPT[oo]);
            aT[oo] = fmaf(gw, tf, aT[oo]);
          }
        }
      }
#pragma unroll
      for (int oo = 0; oo < 8; ++oo) {
        int r = rb + oo;
        __half2 a = __floats2half2_rn(aP[oo], aP2[oo]);
        __half2 bb = __floats2half2_rn(aPT[oo], aT[oo]);
        vOutU[0][r][col] = *(const unsigned*)&a;
        vOutU[1][r][col] = *(const unsigned*)&bb;
      }
    }
    __syncthreads();

    // ---- phase 2: stage(c+1) issue early + horizontal conv + SSIM
    const bool more = (c + 1) < c1;
    unsigned R2[6];
    if (more) {
      const __half* pn = pH + (size_t)(b * C + c + 1) * HW;
#pragma unroll
      for (int k = 0; k < 6; ++k) {
        int w = tid + k * 256;
        unsigned v = 0;
        if (w < IH * IW / 2) {
          int r = w >> 5, cw = w & 31;
          v = *(const unsigned*)(pn + min(y0 + r, H - 1) * W +
                                 min(x0 + 2 * cw, W - 2));
        }
        R2[k] = v;
      }
    }

    float acc = 0.0f;
    if (rb < oh) {
      float mu1[8] = {}, dp2[8] = {}, dpt[8] = {}, mu2[8] = {};
#pragma unroll
      for (int gsel = 0; gsel < 2; ++gsel) {
        unsigned vin[18];
#pragma unroll
        for (int k = 0; k < 18; ++k) vin[k] = vOutU[gsel][prow][cbase + k];
#pragma unroll
        for (int j = 0; j < 18; ++j) {
          __half2 hv = *(const __half2*)&vin[j];
          float lo = __low2float(hv), hi = __high2float(hv);
#pragma unroll
          for (int oo = 0; oo < 8; ++oo) {
            int g = j - oo;
            if (g >= 0 && g < 11) {
              float gw = G[g];
              if (gsel == 0) {
                mu1[oo] = fmaf(gw, lo, mu1[oo]);
                dp2[oo] = fmaf(gw, hi, dp2[oo]);
              } else {
                dpt[oo] = fmaf(gw, lo, dpt[oo]);
                mu2[oo] = fmaf(gw, hi, mu2[oo]);
              }
            }
          }
        }
      }
      if (prow < oh) {
#pragma unroll
        for (int oo = 0; oo < 8; ++oo) {
          if (cbase + oo < ow) {
            float m1 = mu1[oo], m2 = mu2[oo];
            float m1s = m1 * m1, m2s = m2 * m2, m12 = m1 * m2;
            float v1 = dp2[oo] - m1s;
            float v2 = m2 - m2s;  // t one-hot: dwconv(t^2) == mu2
            float cv = dpt[oo] - m12;
            float num = (2.f * m12 + 1e-4f) * (2.f * cv + 9e-4f);
            float den = (m1s + m2s + 1e-4f) * (v1 + v2 + 9e-4f);
            acc += __fdividef(num, den);
          }
        }
      }
      for (int o2 = 32; o2 > 0; o2 >>= 1) acc += __shfl_down(acc, o2);
      if ((tid & 63) == 0) atomicAdd(accp + c, acc);
    }

    if (more) {  // write-late: phase-1 readers of pTu done at mid barrier
#pragma unroll
      for (int k = 0; k < 6; ++k) {
        int w = tid + k * 256;
        if (w < IH * IW / 2) pTu[w] = R2[k];
      }
    }
  }
}

// ===========================================================================
// FALLBACK PATH (R3 design, ~10.5 MiB workspace) — used only if ws too small
// ===========================================================================

__global__ __launch_bounds__(256) void denom_kernel(
    const float* __restrict__ pred, const int* __restrict__ target,
    float* __restrict__ rs, unsigned char* __restrict__ t8,
    float* __restrict__ accum) {
  int tid = blockIdx.x * 256 + threadIdx.x;
  if (blockIdx.x == 0 && threadIdx.x < B * C) accum[threadIdx.x] = 0.0f;
  int p4 = tid * 4;
  int b = p4 / HW;
  int px = p4 - b * HW;
  const float4* pp = (const float4*)(pred + (size_t)b * C * HW + px);
  float4 s = {0.f, 0.f, 0.f, 0.f};
#pragma unroll
  for (int c = 0; c < C; ++c) {
    float4 v = pp[c * (HW / 4)];
    s.x += __expf(v.x);
    s.y += __expf(v.y);
    s.z += __expf(v.z);
    s.w += __expf(v.w);
  }
  float4 r;
  r.x = 1.0f / s.x; r.y = 1.0f / s.y; r.z = 1.0f / s.z; r.w = 1.0f / s.w;
  ((float4*)rs)[tid] = r;
  int4 t = ((const int4*)target)[tid];
  uchar4 tc;
  tc.x = (unsigned char)t.x; tc.y = (unsigned char)t.y;
  tc.z = (unsigned char)t.z; tc.w = (unsigned char)t.w;
  ((uchar4*)t8)[tid] = tc;
}

__global__ __launch_bounds__(256)
__attribute__((amdgpu_waves_per_eu(4, 4))) void ssim_f32_kernel(
    const float* __restrict__ pred, const float* __restrict__ rs,
    const unsigned char* __restrict__ t8, float* __restrict__ accum) {
  __shared__ float vOut[4][TH][68];
  const int tid = threadIdx.x;
  const int x0 = blockIdx.x * TW;
  const int y0 = blockIdx.y * TH;
  const int z = blockIdx.z;
  const int b = z >> 2;
  const int c0 = (z & 3) * 5;
  const int c1 = min(c0 + 5, C);
  const int ow = min(TW, OW - x0);
  const int oh = min(TH, OH - y0);
  const int col = tid & 63;
  const int rg = tid >> 6;
  const int gc = min(x0 + col, W - 1);
  const int rbase = y0 + rg * 8;
  const int prow = tid >> 3;
  const int cg = tid & 7;
  const int cbase = cg * 7;
  const float* rsb = rs + b * HW;
  const unsigned char* tb = t8 + b * HW;

  for (int c = c0; c < c1; ++c) {
    __syncthreads();
    const float* pc = pred + (size_t)(b * C + c) * HW;
    float aP[8] = {}, aP2[8] = {}, aPT[8] = {}, aT[8] = {};
#pragma unroll
    for (int j = 0; j < 18; ++j) {
      int r = min(rbase + j, H - 1);
      int o = r * W + gc;
      float p = __expf(pc[o]) * rsb[o];
      float p2 = p * p;
      bool hit = ((int)tb[o] == c);
      float tf = hit ? 1.0f : 0.0f;
      float pt = hit ? p : 0.0f;
#pragma unroll
      for (int oo = 0; oo < 8; ++oo) {
        int g = j - oo;
        if (g >= 0 && g < 11) {
          float gw = G[g];
          aP[oo] = fmaf(gw, p, aP[oo]);
          aP2[oo] = fmaf(gw, p2, aP2[oo]);
          aPT[oo] = fmaf(gw, pt, aPT[oo]);
          aT[oo] = fmaf(gw, tf, aT[oo]);
        }
      }
    }
#pragma unroll
    for (int oo = 0; oo < 8; ++oo) {
      int r = rg * 8 + oo;
      vOut[0][r][col] = aP[oo];
      vOut[1][r][col] = aP2[oo];
      vOut[2][r][col] = aPT[oo];
      vOut[3][r][col] = aT[oo];
    }
    __syncthreads();

    float mres[4][7];
#pragma unroll
    for (int f = 0; f < 4; ++f) {
      float vin[17];
#pragma unroll
      for (int k = 0; k < 17; ++k) vin[k] = vOut[f][prow][cbase + k];
#pragma unroll
      for (int oo = 0; oo < 7; ++oo) {
        float s = 0.0f;
#pragma unroll
        for (int j = 0; j < 11; ++j) s = fmaf(G[j], vin[oo + j], s);
        mres[f][oo] = s;
      }
    }
    float acc = 0.0f;
    if (prow < oh) {
#pragma unroll
      for (int oo = 0; oo < 7; ++oo) {
        if (cbase + oo < ow) {
          float m1 = mres[0][oo], m2 = mres[3][oo];
          float m1s = m1 * m1, m2s = m2 * m2, m12 = m1 * m2;
          float v1 = mres[1][oo] - m1s;
          float v2 = m2 - m2s;
          float cv = mres[2][oo] - m12;
          float num = (2.f * m12 + 1e-4f) * (2.f * cv + 9e-4f);
          float den = (m1s + m2s + 1e-4f) * (v1 + v2 + 9e-4f);
          acc += __fdividef(num, den);
        }
      }
    }
    for (int o2 = 32; o2 > 0; o2 >>= 1) acc += __shfl_down(acc, o2);
    if ((tid & 63) == 0) atomicAdd(&accum[b * C + c], acc);
  }
}

// K3: final reduction: per-(b,c) mean, relu, 1 - mean
__global__ __launch_bounds__(256) void finish_kernel(
    const float* __restrict__ accum, float* __restrict__ out) {
  __shared__ float red[4];
  int tid = threadIdx.x;
  float v = 0.0f;
  if (tid < B * C) {
    float m = accum[tid] * (1.0f / (float)(OH * OW));
    v = m > 0.0f ? m : 0.0f;
  }
  for (int off = 32; off > 0; off >>= 1) v += __shfl_down(v, off);
  if ((tid & 63) == 0) red[tid >> 6] = v;
  __syncthreads();
  if (tid == 0)
    out[0] = 1.0f - (red[0] + red[1] + red[2] + red[3]) / (float)(B * C);
}

}  // namespace

extern "C" void kernel_launch(void* const* d_in, const int* in_sizes, int n_in,
                              void* d_out, int out_size, void* d_ws,
                              size_t ws_size, hipStream_t stream) {
  const float* pred = (const float*)d_in[0];
  const int* target = (const int*)d_in[1];
  float* out = (float*)d_out;

  const size_t needH = (size_t)B * C * HW * 2 + (size_t)B * C * 4;
  dim3 grid((OW + TW - 1) / TW, (OH + TH - 1) / TH, B * 4);

  if (ws_size >= needH) {
    // primary: pH (76 MiB f16) | accum
    __half* pH = (__half*)d_ws;
    float* accum = (float*)((char*)d_ws + (size_t)B * C * HW * 2);
    softmax_kernel<<<B * HW / 512, 256, 0, stream>>>(pred, pH, accum);
    ssim_kernel<<<grid, 256, 0, stream>>>(pH, target, accum);
    finish_kernel<<<1, 256, 0, stream>>>(accum, out);
  } else {
    // fallback: rs (8 MiB f32) | t8 (2 MiB u8) | accum
    float* rs = (float*)d_ws;
    unsigned char* t8 = (unsigned char*)d_ws + (size_t)B * HW * 4;
    float* accum = (float*)((char*)d_ws + (size_t)B * HW * 5);
    denom_kernel<<<B * HW / 1024, 256, 0, stream>>>(pred, target, rs, t8,
                                                    accum);
    ssim_f32_kernel<<<grid, 256, 0, stream>>>(pred, rs, t8, accum);
    finish_kernel<<<1, 256, 0, stream>>>(accum, out);
  }
}